// Round 9
// baseline (86.927 us; speedup 1.0000x reference)
//
#include <hip/hip_runtime.h>

// Fused Swin shifted-window MSA. Round 9: ONE WAVE = ONE WINDOW (64-thr blocks,
// grid 2048, zero barriers). Each wave computes all 4 heads' Q,K,V, attention,
// and feeds out-proj from registers. Key derivation: out-proj k-step kk spans
// d=[32kk,32kk+32) = head kk's O, and O D-layout -> out-proj B-frag is the SAME
// redist template verified since round 4 (srcA/srcB words, hiSel=dn). LDS = Xs
// only (17.4KB) -> 9 blocks/CU; 8 windows/CU => whole grid co-resident.

#define HWD 56
#define SCALE_Q 0.17677669529663687f   // 1/sqrt(32)

typedef _Float16 f16x8 __attribute__((ext_vector_type(8)));
typedef __fp16   h16x2 __attribute__((ext_vector_type(2)));   // cvt_pkrtz return type
typedef float    f32x4 __attribute__((ext_vector_type(4)));

__device__ __forceinline__ unsigned pkrtz(float a, float b) {
    union { h16x2 h; unsigned u; } r;
    r.h = __builtin_amdgcn_cvt_pkrtz(a, b);
    return r.u;
}

__device__ __forceinline__ f32x4 mfma16(const unsigned a[4], const unsigned b[4], f32x4 c) {
    union { unsigned u[4]; f16x8 h; } A, B;
    A.u[0] = a[0]; A.u[1] = a[1]; A.u[2] = a[2]; A.u[3] = a[3];
    B.u[0] = b[0]; B.u[1] = b[1]; B.u[2] = b[2]; B.u[3] = b[3];
    return __builtin_amdgcn_mfma_f32_16x16x32_f16(A.h, B.h, c, 0, 0, 0);
}

__device__ __forceinline__ unsigned short f16b(float v) {
    union { _Float16 h; unsigned short s; } cv; cv.h = (_Float16)v; return cv.s;
}

// whQKV: f16 [384][128] (rows 0..127 pre-scaled by 1/sqrt(hd))
// whP  : f16 [128][128]
// biasT: f32 [wtype][head][i][j]  (rel-pos bias + shift mask + key-pad mask)
__global__ void prep2(const float* __restrict__ rpb,
                      const float* __restrict__ w_qkv,
                      const float* __restrict__ w_proj,
                      unsigned short* __restrict__ whQKV,
                      unsigned short* __restrict__ whP,
                      float* __restrict__ biasT)
{
    int idx = blockIdx.x * 256 + threadIdx.x;               // 131072 total
    if (idx < 49152) {
        float v = w_qkv[idx];
        if (idx < 16384) v *= SCALE_Q;                      // q rows 0..127
        whQKV[idx] = f16b(v);
    } else if (idx < 65536) {
        int j = idx - 49152;
        whP[j] = f16b(w_proj[j]);
    } else {
        int k = idx - 65536;                                // 65536 bias elems
        int j = k & 63, i = (k >> 6) & 63, h = (k >> 12) & 3, t = k >> 14;
        float v;
        if (j >= 49)      v = -1e30f;                       // key padding
        else if (i >= 49) v = 0.f;                          // query padding (don't care)
        else {
            int ri = i / 7, ci = i % 7, rj = j / 7, cj = j % 7;
            int rel = (ri - rj + 6) * 13 + (ci - cj + 6);
            v = rpb[rel * 4 + h];
            int gi = ((t & 2) ? (ri < 4 ? 1 : 2) : 0) * 3 + ((t & 1) ? (ci < 4 ? 1 : 2) : 0);
            int gj = ((t & 2) ? (rj < 4 ? 1 : 2) : 0) * 3 + ((t & 1) ? (cj < 4 ? 1 : 2) : 0);
            if (gi != gj) v -= 100.f;
        }
        biasT[k] = v;
    }
}

__global__ __launch_bounds__(64, 3)
void swin_msa_win1(const float* __restrict__ x,
                   const unsigned short* __restrict__ whQKV,
                   const unsigned short* __restrict__ whP,
                   const float* __restrict__ b_proj,
                   const float* __restrict__ biasT,
                   float* __restrict__ out)
{
    // Xs: f16 window input [tok 0..63][ch 0..127] stride 136 halves (16B rows).
    __shared__ __align__(16) unsigned short Xs[64 * 136];    // 17408 B

    const int lane = threadIdx.x;      // single wave
    const int c    = lane & 15;
    const int g    = lane >> 4;

    const int blk  = blockIdx.x;
    const int b    = blk >> 6;
    const int wIdx = blk & 63;
    const int wh   = wIdx >> 3, ww = wIdx & 7;
    const int wtype = ((wh == 7) ? 2 : 0) | ((ww == 7) ? 1 : 0);

    auto tokAddr = [&](int tok) {      // tok must be < 49
        int rr = tok / 7, cc = tok - rr * 7;
        int sh = wh * 7 + rr + 3; if (sh >= HWD) sh -= HWD;
        int sw = ww * 7 + cc + 3; if (sw >= HWD) sw -= HWD;
        return ((b * HWD + sh) * HWD + sw) * 128;
    };

    // ---- stage X: 32 iters (64 lanes), f32->f16; same-wave -> no barrier
    for (int idx = lane; idx < 2048; idx += 64) {
        int tok = idx >> 5, ch4 = (idx & 31) << 2;
        uint2 wv = make_uint2(0u, 0u);                      // zero pad rows 49..63
        if (tok < 49) {
            const float4 v = *(const float4*)(x + tokAddr(tok) + ch4);
            wv = make_uint2(pkrtz(v.x, v.y), pkrtz(v.z, v.w));
        }
        *(uint2*)&Xs[tok * 136 + ch4] = wv;
    }

    const int srcA  = c | ((lane & 16) << 1);  // lane (c, 2*(g&1))
    const int srcB  = srcA + 16;               // lane (c, 2*(g&1)+1)
    const bool hiSel = (lane & 32) != 0;       // g>>1 selects the tile-pair member

    // D->frag redistribution template (verified rounds 4..8):
    auto redist = [&](const unsigned pkLo[2], const unsigned pkHi[2], unsigned f[4]) {
        #pragma unroll
        for (int p = 0; p < 2; ++p) {
            unsigned lo0 = __shfl(pkLo[p], srcA);
            unsigned hi0 = __shfl(pkHi[p], srcA);
            f[p] = hiSel ? hi0 : lo0;
            unsigned lo1 = __shfl(pkLo[p], srcB);
            unsigned hi1 = __shfl(pkHi[p], srcB);
            f[2 + p] = hiSel ? hi1 : lo1;
        }
    };
    auto loadW = [&](const unsigned short* wbase, int rowBase, unsigned af[4][4]) {
        const unsigned short* wr = wbase + (rowBase + c) * 128 + g * 8;
        #pragma unroll
        for (int kk = 0; kk < 4; ++kk) {
            uint4 v = *(const uint4*)(wr + kk * 32);
            af[kk][0] = v.x; af[kk][1] = v.y; af[kk][2] = v.z; af[kk][3] = v.w;
        }
    };
    auto xfrag = [&](int nt, unsigned xB[4][4]) {
        const unsigned short* xr = &Xs[(nt * 16 + c) * 136 + g * 8];
        #pragma unroll
        for (int kk = 0; kk < 4; ++kk) {
            uint4 v = *(const uint4*)(xr + kk * 32);
            xB[kk][0] = v.x; xB[kk][1] = v.y; xB[kk][2] = v.z; xB[kk][3] = v.w;
        }
    };

    // oB[head][nt] = out-proj B-frag of head's O (filled per head below)
    unsigned oB[4][4][4];

    #pragma unroll
    for (int h = 0; h < 4; ++h) {
        // ---- own-head Q,K,V GEMMs + in-register redistribution
        unsigned qB[4][4], kA[4][4], vA[2][2][4];
        {
            unsigned pkP[2][4][2];
            #pragma unroll
            for (int ql = 0; ql < 2; ++ql) {                 // Q: mfma(Wq, X)
                unsigned af[4][4];
                loadW(whQKV, 32 * h + 16 * ql, af);
                #pragma unroll
                for (int nt = 0; nt < 4; ++nt) {
                    unsigned xB[4][4]; xfrag(nt, xB);
                    f32x4 acc = {0.f, 0.f, 0.f, 0.f};
                    #pragma unroll
                    for (int kk = 0; kk < 4; ++kk) acc = mfma16(af[kk], xB[kk], acc);
                    pkP[ql][nt][0] = pkrtz(acc[0], acc[1]);
                    pkP[ql][nt][1] = pkrtz(acc[2], acc[3]);
                }
            }
            #pragma unroll
            for (int nt = 0; nt < 4; ++nt) redist(pkP[0][nt], pkP[1][nt], qB[nt]);

            #pragma unroll
            for (int kl = 0; kl < 2; ++kl) {                 // K: mfma(Wk, X)
                unsigned af[4][4];
                loadW(whQKV, 128 + 32 * h + 16 * kl, af);
                #pragma unroll
                for (int mt = 0; mt < 4; ++mt) {
                    unsigned xB[4][4]; xfrag(mt, xB);
                    f32x4 acc = {0.f, 0.f, 0.f, 0.f};
                    #pragma unroll
                    for (int kk = 0; kk < 4; ++kk) acc = mfma16(af[kk], xB[kk], acc);
                    pkP[kl][mt][0] = pkrtz(acc[0], acc[1]);
                    pkP[kl][mt][1] = pkrtz(acc[2], acc[3]);
                }
            }
            #pragma unroll
            for (int mt = 0; mt < 4; ++mt) redist(pkP[0][mt], pkP[1][mt], kA[mt]);
        }
        #pragma unroll
        for (int vl = 0; vl < 2; ++vl) {                     // V: mfma(X, Wv)
            unsigned bf[4][4];
            loadW(whQKV, 256 + 32 * h + 16 * vl, bf);
            unsigned pkV[4][2];
            #pragma unroll
            for (int mt = 0; mt < 4; ++mt) {
                unsigned xA[4][4]; xfrag(mt, xA);
                f32x4 acc = {0.f, 0.f, 0.f, 0.f};
                #pragma unroll
                for (int kk = 0; kk < 4; ++kk) acc = mfma16(xA[kk], bf[kk], acc);
                pkV[mt][0] = pkrtz(acc[0], acc[1]);
                pkV[mt][1] = pkrtz(acc[2], acc[3]);
            }
            #pragma unroll
            for (int kv = 0; kv < 2; ++kv)
                redist(pkV[2 * kv], pkV[2 * kv + 1], vA[vl][kv]);
        }

        // ---- attention, per-i-tile fused; O-tile immediately -> oB[h][nt]
        const float* bT = biasT + (wtype * 4 + h) * 4096;    // [i][j]
        #pragma unroll
        for (int nt = 0; nt < 4; ++nt) {
            f32x4 S[4];                // S^T: lane j=16mt+4g+r, i=16nt+c
            #pragma unroll
            for (int mt = 0; mt < 4; ++mt) {
                float4 b4 = *(const float4*)&bT[(nt * 16 + c) * 64 + mt * 16 + 4 * g];
                f32x4 C = { b4.x, b4.y, b4.z, b4.w };        // bias as MFMA C-operand
                S[mt] = mfma16(kA[mt], qB[nt], C);
            }
            float m = -1e30f;
            #pragma unroll
            for (int mt = 0; mt < 4; ++mt)
                #pragma unroll
                for (int r = 0; r < 4; ++r) m = fmaxf(m, S[mt][r]);
            m = fmaxf(m, __shfl_xor(m, 16));
            m = fmaxf(m, __shfl_xor(m, 32));
            float s = 0.f;
            #pragma unroll
            for (int mt = 0; mt < 4; ++mt)
                #pragma unroll
                for (int r = 0; r < 4; ++r) { float e = __expf(S[mt][r] - m); S[mt][r] = e; s += e; }
            s += __shfl_xor(s, 16);
            s += __shfl_xor(s, 32);
            const float iv = 1.0f / s;

            f32x4 o0 = {0.f, 0.f, 0.f, 0.f};
            f32x4 o1 = {0.f, 0.f, 0.f, 0.f};
            #pragma unroll
            for (int kk = 0; kk < 2; ++kk) {
                unsigned pkLo[2], pkHi[2];
                pkLo[0] = pkrtz(S[2 * kk][0] * iv,     S[2 * kk][1] * iv);
                pkLo[1] = pkrtz(S[2 * kk][2] * iv,     S[2 * kk][3] * iv);
                pkHi[0] = pkrtz(S[2 * kk + 1][0] * iv, S[2 * kk + 1][1] * iv);
                pkHi[1] = pkrtz(S[2 * kk + 1][2] * iv, S[2 * kk + 1][3] * iv);
                unsigned pB[4];
                redist(pkLo, pkHi, pB);
                o0 = mfma16(vA[0][kk], pB, o0);
                o1 = mfma16(vA[1][kk], pB, o1);
            }
            // O D-layout -> out-proj B-frag: SAME redist template
            // (word q: srcA/srcB by q>>1, source word q&1, dn selected by hiSel)
            unsigned OpkLo[2] = { pkrtz(o0[0], o0[1]), pkrtz(o0[2], o0[3]) };  // dn=0
            unsigned OpkHi[2] = { pkrtz(o1[0], o1[1]), pkrtz(o1[2], o1[3]) };  // dn=1
            redist(OpkLo, OpkHi, oB[h][nt]);
        }
    }

    // ================= out-proj: OUT = O @ Wproj^T + b (kstep kk = head kk) ==
    int taddr[4];
    #pragma unroll
    for (int nt = 0; nt < 4; ++nt) {
        int tok = nt * 16 + c;
        taddr[nt] = (tok < 49) ? tokAddr(tok) : -1;
    }
    #pragma unroll
    for (int mt = 0; mt < 8; ++mt) {
        unsigned aW[4][4];
        loadW(whP, 16 * mt, aW);
        float4 bias4 = *(const float4*)(b_proj + mt * 16 + 4 * g);
        #pragma unroll
        for (int nt = 0; nt < 4; ++nt) {
            f32x4 acc = {0.f, 0.f, 0.f, 0.f};
            #pragma unroll
            for (int kk = 0; kk < 4; ++kk) acc = mfma16(aW[kk], oB[kk][nt], acc);
            if (taddr[nt] >= 0) {
                float4 o = make_float4(acc[0] + bias4.x, acc[1] + bias4.y,
                                       acc[2] + bias4.z, acc[3] + bias4.w);
                *(float4*)(out + taddr[nt] + mt * 16 + 4 * g) = o;
            }
        }
    }
}

extern "C" void kernel_launch(void* const* d_in, const int* in_sizes, int n_in,
                              void* d_out, int out_size, void* d_ws, size_t ws_size,
                              hipStream_t stream) {
    const float* x     = (const float*)d_in[0];
    const float* rpb   = (const float*)d_in[1];
    const float* wqkv  = (const float*)d_in[2];
    const float* wproj = (const float*)d_in[3];
    const float* bproj = (const float*)d_in[4];
    float* outp = (float*)d_out;

    unsigned short* whQKV = (unsigned short*)d_ws;          // 49152 halves
    unsigned short* whP   = whQKV + 49152;                  // 16384 halves
    float* biasT = (float*)(whP + 16384);                   // 65536 f32

    prep2<<<512, 256, 0, stream>>>(rpb, wqkv, wproj, whQKV, whP, biasT);
    swin_msa_win1<<<2048, 64, 0, stream>>>(x, whQKV, whP, bproj, biasT, outp);
}

// Round 10
// 65.134 us; speedup vs baseline: 1.3346x; 1.3346x over previous
//
#include <hip/hip_runtime.h>

// Fused Swin shifted-window MSA, one workgroup (4 waves) per 7x7 window.
// Round 10: revert to round-8 structure (best, 69us) + latency-overlap attack:
//  - phase A weight streams PAIRED (af0+af1 loaded together, MFMA chains
//    interleaved; xfrag LDS reads halved 96->48)
//  - attention bias loads software-pipelined one nt ahead
//  - out-proj aW streams paired up front
//  - s_setprio(1) around MFMA clusters (T5)
//  - __launch_bounds__(256,4): 128-reg quantum boundary; new peak live ~120.
// Diagnostic: WRITE_SIZE 52-58MB = clean; >65MB = spills returned.

#define HWD 56
#define SCALE_Q 0.17677669529663687f   // 1/sqrt(32)

typedef _Float16 f16x8 __attribute__((ext_vector_type(8)));
typedef __fp16   h16x2 __attribute__((ext_vector_type(2)));   // cvt_pkrtz return type
typedef float    f32x4 __attribute__((ext_vector_type(4)));

__device__ __forceinline__ unsigned pkrtz(float a, float b) {
    union { h16x2 h; unsigned u; } r;
    r.h = __builtin_amdgcn_cvt_pkrtz(a, b);
    return r.u;
}

__device__ __forceinline__ f32x4 mfma16(const unsigned a[4], const unsigned b[4], f32x4 c) {
    union { unsigned u[4]; f16x8 h; } A, B;
    A.u[0] = a[0]; A.u[1] = a[1]; A.u[2] = a[2]; A.u[3] = a[3];
    B.u[0] = b[0]; B.u[1] = b[1]; B.u[2] = b[2]; B.u[3] = b[3];
    return __builtin_amdgcn_mfma_f32_16x16x32_f16(A.h, B.h, c, 0, 0, 0);
}

__device__ __forceinline__ unsigned short f16b(float v) {
    union { _Float16 h; unsigned short s; } cv; cv.h = (_Float16)v; return cv.s;
}

// whQKV: f16 [384][128] (rows 0..127 pre-scaled by 1/sqrt(hd))
// whP  : f16 [128][128]
// biasT: f32 [wtype][head][i][j]  (rel-pos bias + shift mask + key-pad mask)
__global__ void prep2(const float* __restrict__ rpb,
                      const float* __restrict__ w_qkv,
                      const float* __restrict__ w_proj,
                      unsigned short* __restrict__ whQKV,
                      unsigned short* __restrict__ whP,
                      float* __restrict__ biasT)
{
    int idx = blockIdx.x * 256 + threadIdx.x;               // 131072 total
    if (idx < 49152) {
        float v = w_qkv[idx];
        if (idx < 16384) v *= SCALE_Q;                      // q rows 0..127
        whQKV[idx] = f16b(v);
    } else if (idx < 65536) {
        int j = idx - 49152;
        whP[j] = f16b(w_proj[j]);
    } else {
        int k = idx - 65536;                                // 65536 bias elems
        int j = k & 63, i = (k >> 6) & 63, h = (k >> 12) & 3, t = k >> 14;
        float v;
        if (j >= 49)      v = -1e30f;                       // key padding
        else if (i >= 49) v = 0.f;                          // query padding (don't care)
        else {
            int ri = i / 7, ci = i % 7, rj = j / 7, cj = j % 7;
            int rel = (ri - rj + 6) * 13 + (ci - cj + 6);
            v = rpb[rel * 4 + h];
            int gi = ((t & 2) ? (ri < 4 ? 1 : 2) : 0) * 3 + ((t & 1) ? (ci < 4 ? 1 : 2) : 0);
            int gj = ((t & 2) ? (rj < 4 ? 1 : 2) : 0) * 3 + ((t & 1) ? (cj < 4 ? 1 : 2) : 0);
            if (gi != gj) v -= 100.f;
        }
        biasT[k] = v;
    }
}

__global__ __launch_bounds__(256, 4)
void swin_msa_mfma7(const float* __restrict__ x,
                    const unsigned short* __restrict__ whQKV,
                    const unsigned short* __restrict__ whP,
                    const float* __restrict__ b_proj,
                    const float* __restrict__ biasT,
                    float* __restrict__ out)
{
    // Xs: f16 window input [tok 0..63][ch 0..127] stride 136 halves.
    // Osh: attention output exchange, same geometry.
    __shared__ __align__(16) unsigned short Xs[64 * 136];    // 17408 B
    __shared__ __align__(16) unsigned short Osh[64 * 136];   // 17408 B

    const int tid  = threadIdx.x;
    const int h    = tid >> 6;         // wave id == head
    const int lane = tid & 63;
    const int c    = lane & 15;
    const int g    = lane >> 4;

    const int blk  = blockIdx.x;
    const int b    = blk >> 6;
    const int wIdx = blk & 63;
    const int wh   = wIdx >> 3, ww = wIdx & 7;
    const int wtype = ((wh == 7) ? 2 : 0) | ((ww == 7) ? 1 : 0);

    auto tokAddr = [&](int tok) {      // tok must be < 49
        int rr = tok / 7, cc = tok - rr * 7;
        int sh = wh * 7 + rr + 3; if (sh >= HWD) sh -= HWD;
        int sw = ww * 7 + cc + 3; if (sw >= HWD) sw -= HWD;
        return ((b * HWD + sh) * HWD + sw) * 128;
    };

    // ---- stage X: coalesced (32 lanes cover one 512B token row), f32->f16
    for (int idx = tid; idx < 2048; idx += 256) {
        int tok = idx >> 5, ch4 = (idx & 31) << 2;
        uint2 wv = make_uint2(0u, 0u);                      // zero pad rows 49..63
        if (tok < 49) {
            const float4 v = *(const float4*)(x + tokAddr(tok) + ch4);
            wv = make_uint2(pkrtz(v.x, v.y), pkrtz(v.z, v.w));
        }
        *(uint2*)&Xs[tok * 136 + ch4] = wv;
    }
    __syncthreads();                   // barrier 1: X ready

    const int srcA  = c | ((lane & 16) << 1);  // lane (c, 2*(g&1))
    const int srcB  = srcA + 16;               // lane (c, 2*(g&1)+1)
    const bool hiSel = (lane & 32) != 0;       // g>>1 selects the tile-pair member

    // D->frag redistribution template (verified rounds 4..9):
    auto redist = [&](const unsigned pkLo[2], const unsigned pkHi[2], unsigned f[4]) {
        #pragma unroll
        for (int p = 0; p < 2; ++p) {
            unsigned lo0 = __shfl(pkLo[p], srcA);
            unsigned hi0 = __shfl(pkHi[p], srcA);
            f[p] = hiSel ? hi0 : lo0;
            unsigned lo1 = __shfl(pkLo[p], srcB);
            unsigned hi1 = __shfl(pkHi[p], srcB);
            f[2 + p] = hiSel ? hi1 : lo1;
        }
    };
    auto loadW = [&](const unsigned short* wbase, int rowBase, unsigned af[4][4]) {
        const unsigned short* wr = wbase + (rowBase + c) * 128 + g * 8;
        #pragma unroll
        for (int kk = 0; kk < 4; ++kk) {
            uint4 v = *(const uint4*)(wr + kk * 32);
            af[kk][0] = v.x; af[kk][1] = v.y; af[kk][2] = v.z; af[kk][3] = v.w;
        }
    };
    auto xfrag = [&](int nt, unsigned xB[4][4]) {
        const unsigned short* xr = &Xs[(nt * 16 + c) * 136 + g * 8];
        #pragma unroll
        for (int kk = 0; kk < 4; ++kk) {
            uint4 v = *(const uint4*)(xr + kk * 32);
            xB[kk][0] = v.x; xB[kk][1] = v.y; xB[kk][2] = v.z; xB[kk][3] = v.w;
        }
    };

    // ================= phase A: own-head Q,K,V (paired streams) ========
    unsigned qB[4][4];                 // B[k=d][n=i] per i-tile nt
    unsigned kA[4][4];                 // A[m=j][k=d] per j-tile mt
    unsigned vA[2][2][4];              // A[m=d][k=j] per (d-tile, j-chunk)
    {
        unsigned pkP[2][4][2];
        unsigned af0[4][4], af1[4][4];
        // --- Q: both ql streams loaded together, MFMA chains interleaved
        loadW(whQKV, 32 * h,      af0);
        loadW(whQKV, 32 * h + 16, af1);
        __builtin_amdgcn_s_setprio(1);
        #pragma unroll
        for (int nt = 0; nt < 4; ++nt) {
            unsigned xB[4][4]; xfrag(nt, xB);
            f32x4 a0 = {0.f, 0.f, 0.f, 0.f};
            f32x4 a1 = {0.f, 0.f, 0.f, 0.f};
            #pragma unroll
            for (int kk = 0; kk < 4; ++kk) {
                a0 = mfma16(af0[kk], xB[kk], a0);
                a1 = mfma16(af1[kk], xB[kk], a1);
            }
            pkP[0][nt][0] = pkrtz(a0[0], a0[1]); pkP[0][nt][1] = pkrtz(a0[2], a0[3]);
            pkP[1][nt][0] = pkrtz(a1[0], a1[1]); pkP[1][nt][1] = pkrtz(a1[2], a1[3]);
        }
        __builtin_amdgcn_s_setprio(0);
        #pragma unroll
        for (int nt = 0; nt < 4; ++nt) redist(pkP[0][nt], pkP[1][nt], qB[nt]);

        // --- K: paired kl streams
        loadW(whQKV, 128 + 32 * h,      af0);
        loadW(whQKV, 128 + 32 * h + 16, af1);
        __builtin_amdgcn_s_setprio(1);
        #pragma unroll
        for (int mt = 0; mt < 4; ++mt) {
            unsigned xB[4][4]; xfrag(mt, xB);
            f32x4 a0 = {0.f, 0.f, 0.f, 0.f};
            f32x4 a1 = {0.f, 0.f, 0.f, 0.f};
            #pragma unroll
            for (int kk = 0; kk < 4; ++kk) {
                a0 = mfma16(af0[kk], xB[kk], a0);
                a1 = mfma16(af1[kk], xB[kk], a1);
            }
            pkP[0][mt][0] = pkrtz(a0[0], a0[1]); pkP[0][mt][1] = pkrtz(a0[2], a0[3]);
            pkP[1][mt][0] = pkrtz(a1[0], a1[1]); pkP[1][mt][1] = pkrtz(a1[2], a1[3]);
        }
        __builtin_amdgcn_s_setprio(0);
        #pragma unroll
        for (int mt = 0; mt < 4; ++mt) redist(pkP[0][mt], pkP[1][mt], kA[mt]);

        // --- V: paired vl streams; mfma(X, Wv) -> D[tok][d]
        loadW(whQKV, 256 + 32 * h,      af0);
        loadW(whQKV, 256 + 32 * h + 16, af1);
        unsigned pkV0[4][2], pkV1[4][2];
        __builtin_amdgcn_s_setprio(1);
        #pragma unroll
        for (int mt = 0; mt < 4; ++mt) {
            unsigned xA[4][4]; xfrag(mt, xA);
            f32x4 a0 = {0.f, 0.f, 0.f, 0.f};
            f32x4 a1 = {0.f, 0.f, 0.f, 0.f};
            #pragma unroll
            for (int kk = 0; kk < 4; ++kk) {
                a0 = mfma16(xA[kk], af0[kk], a0);
                a1 = mfma16(xA[kk], af1[kk], a1);
            }
            pkV0[mt][0] = pkrtz(a0[0], a0[1]); pkV0[mt][1] = pkrtz(a0[2], a0[3]);
            pkV1[mt][0] = pkrtz(a1[0], a1[1]); pkV1[mt][1] = pkrtz(a1[2], a1[3]);
        }
        __builtin_amdgcn_s_setprio(0);
        #pragma unroll
        for (int kv = 0; kv < 2; ++kv) {
            redist(pkV0[2 * kv], pkV0[2 * kv + 1], vA[0][kv]);
            redist(pkV1[2 * kv], pkV1[2 * kv + 1], vA[1][kv]);
        }
    }

    // ================= attention: per-i-tile fused, bias pipelined =========
    const float* bT = biasT + (wtype * 4 + h) * 4096;       // [i][j]
    float4 bias4[4];
    #pragma unroll
    for (int mt = 0; mt < 4; ++mt)
        bias4[mt] = *(const float4*)&bT[(0 * 16 + c) * 64 + mt * 16 + 4 * g];

    #pragma unroll
    for (int nt = 0; nt < 4; ++nt) {
        float4 biasN[4];
        if (nt < 3) {                  // prefetch next i-tile's bias early
            #pragma unroll
            for (int mt = 0; mt < 4; ++mt)
                biasN[mt] = *(const float4*)&bT[((nt + 1) * 16 + c) * 64 + mt * 16 + 4 * g];
        }
        f32x4 S[4];                    // S^T: lane j=16mt+4g+r, i=16nt+c
        __builtin_amdgcn_s_setprio(1);
        #pragma unroll
        for (int mt = 0; mt < 4; ++mt) {
            f32x4 C = { bias4[mt].x, bias4[mt].y, bias4[mt].z, bias4[mt].w };
            S[mt] = mfma16(kA[mt], qB[nt], C);
        }
        __builtin_amdgcn_s_setprio(0);
        // softmax over j (16 in-lane + 2 butterflies)
        float m = -1e30f;
        #pragma unroll
        for (int mt = 0; mt < 4; ++mt)
            #pragma unroll
            for (int r = 0; r < 4; ++r) m = fmaxf(m, S[mt][r]);
        m = fmaxf(m, __shfl_xor(m, 16));
        m = fmaxf(m, __shfl_xor(m, 32));
        float s = 0.f;
        #pragma unroll
        for (int mt = 0; mt < 4; ++mt)
            #pragma unroll
            for (int r = 0; r < 4; ++r) { float e = __expf(S[mt][r] - m); S[mt][r] = e; s += e; }
        s += __shfl_xor(s, 16);
        s += __shfl_xor(s, 32);
        const float iv = 1.0f / s;

        // PV: pack P per-kk pair only, redist -> B-frag, accumulate o0/o1
        f32x4 o0 = {0.f, 0.f, 0.f, 0.f};
        f32x4 o1 = {0.f, 0.f, 0.f, 0.f};
        #pragma unroll
        for (int kk = 0; kk < 2; ++kk) {
            unsigned pkLo[2], pkHi[2];
            pkLo[0] = pkrtz(S[2 * kk][0] * iv,     S[2 * kk][1] * iv);
            pkLo[1] = pkrtz(S[2 * kk][2] * iv,     S[2 * kk][3] * iv);
            pkHi[0] = pkrtz(S[2 * kk + 1][0] * iv, S[2 * kk + 1][1] * iv);
            pkHi[1] = pkrtz(S[2 * kk + 1][2] * iv, S[2 * kk + 1][3] * iv);
            unsigned pB[4];
            redist(pkLo, pkHi, pB);
            __builtin_amdgcn_s_setprio(1);
            o0 = mfma16(vA[0][kk], pB, o0);
            o1 = mfma16(vA[1][kk], pB, o1);
            __builtin_amdgcn_s_setprio(0);
        }
        // O-tile nt complete -> store now (frees regs, overlaps next nt)
        *(uint2*)&Osh[(nt * 16 + c) * 136 + 32 * h + 4 * g] =
            make_uint2(pkrtz(o0[0], o0[1]), pkrtz(o0[2], o0[3]));
        *(uint2*)&Osh[(nt * 16 + c) * 136 + 32 * h + 16 + 4 * g] =
            make_uint2(pkrtz(o1[0], o1[1]), pkrtz(o1[2], o1[3]));
        if (nt < 3) {
            #pragma unroll
            for (int mt = 0; mt < 4; ++mt) bias4[mt] = biasN[mt];
        }
    }
    __syncthreads();                   // barrier 2: O ready

    // ================= out-proj: OUT = O @ Wproj^T + b (paired aW) =========
    int taddr[4];
    #pragma unroll
    for (int nt = 0; nt < 4; ++nt) {
        int tok = nt * 16 + c;
        taddr[nt] = (tok < 49) ? tokAddr(tok) : -1;
    }
    unsigned aW0[4][4], aW1[4][4];
    loadW(whP, 16 * (2 * h),     aW0);
    loadW(whP, 16 * (2 * h + 1), aW1);
    float4 bb0 = *(const float4*)(b_proj + (2 * h) * 16 + 4 * g);
    float4 bb1 = *(const float4*)(b_proj + (2 * h + 1) * 16 + 4 * g);
    #pragma unroll
    for (int nt = 0; nt < 4; ++nt) {
        unsigned oB[4][4];             // B[k=d][n=i] from O[i][d], this nt only
        #pragma unroll
        for (int kk = 0; kk < 4; ++kk) {
            uint4 v = *(const uint4*)&Osh[(nt * 16 + c) * 136 + kk * 32 + g * 8];
            oB[kk][0] = v.x; oB[kk][1] = v.y; oB[kk][2] = v.z; oB[kk][3] = v.w;
        }
        f32x4 a0 = {0.f, 0.f, 0.f, 0.f};
        f32x4 a1 = {0.f, 0.f, 0.f, 0.f};
        __builtin_amdgcn_s_setprio(1);
        #pragma unroll
        for (int kk = 0; kk < 4; ++kk) {
            a0 = mfma16(aW0[kk], oB[kk], a0);
            a1 = mfma16(aW1[kk], oB[kk], a1);
        }
        __builtin_amdgcn_s_setprio(0);
        if (taddr[nt] >= 0) {
            *(float4*)(out + taddr[nt] + (2 * h) * 16 + 4 * g) =
                make_float4(a0[0] + bb0.x, a0[1] + bb0.y, a0[2] + bb0.z, a0[3] + bb0.w);
            *(float4*)(out + taddr[nt] + (2 * h + 1) * 16 + 4 * g) =
                make_float4(a1[0] + bb1.x, a1[1] + bb1.y, a1[2] + bb1.z, a1[3] + bb1.w);
        }
    }
}

extern "C" void kernel_launch(void* const* d_in, const int* in_sizes, int n_in,
                              void* d_out, int out_size, void* d_ws, size_t ws_size,
                              hipStream_t stream) {
    const float* x     = (const float*)d_in[0];
    const float* rpb   = (const float*)d_in[1];
    const float* wqkv  = (const float*)d_in[2];
    const float* wproj = (const float*)d_in[3];
    const float* bproj = (const float*)d_in[4];
    float* outp = (float*)d_out;

    unsigned short* whQKV = (unsigned short*)d_ws;          // 49152 halves
    unsigned short* whP   = whQKV + 49152;                  // 16384 halves
    float* biasT = (float*)(whP + 16384);                   // 65536 f32

    prep2<<<512, 256, 0, stream>>>(rpb, wqkv, wproj, whQKV, whP, biasT);
    swin_msa_mfma7<<<32 * 64, 256, 0, stream>>>(x, whQKV, whP, bproj, biasT, outp);
}